// Round 8
// baseline (828.741 us; speedup 1.0000x reference)
//
#include <hip/hip_runtime.h>
#include <math.h>

// LightGCN propagation, round 8.
// vs r7 (two isolated changes):
// 1. fill_csr XCD-pinned: blockIdx%8 ~ XCD; each XCD-group scans all edges
//    and claims only entries whose CSR window (offs[row]>>shift) maps to it.
//    All writes to a 4MB window come from one XCD -> its L2 coalesces the
//    8 entries/line -> full-line writebacks (WRITE_SIZE ~253MB -> ~50MB).
//    Heuristic only: wrong mapping degrades to r7 behavior, never wrong.
// 2. prop gather unroll 4 -> 8 (more independent gathers in flight).

__device__ __forceinline__ unsigned short f2bf(float f) {
    unsigned int b = __float_as_uint(f);
    b += 0x7FFFu + ((b >> 16) & 1u);          // round-to-nearest-even
    return (unsigned short)(b >> 16);
}
__device__ __forceinline__ float bf2f(unsigned short u) {
    return __uint_as_float(((unsigned int)u) << 16);
}

__global__ void count_deg_kernel(const int* __restrict__ eu, const int* __restrict__ ei,
                                 int* __restrict__ deg, int E, int NU) {
    int e = blockIdx.x * blockDim.x + threadIdx.x;
    if (e >= E) return;
    atomicAdd(&deg[eu[e]], 1);
    atomicAdd(&deg[NU + ei[e]], 1);
}

__global__ void bump_kernel(const int* __restrict__ deg, int* __restrict__ offs,
                            int* __restrict__ cursor, float* __restrict__ isd,
                            int* __restrict__ total, int n) {
    int i = blockIdx.x * blockDim.x + threadIdx.x;
    if (i >= n) return;
    int d = deg[i];
    int o = atomicAdd(total, d);        // bump alloc; row order irrelevant
    offs[i] = o;
    cursor[i] = o;                      // fill uses cursor directly
    isd[i] = d > 0 ? rsqrtf((float)d) : 0.f;
}

__global__ void conv_bf16_kernel(const float* __restrict__ src,
                                 unsigned short* __restrict__ dst, int n4) {
    int t = blockIdx.x * blockDim.x + threadIdx.x;
    if (t >= n4) return;
    float4 f = ((const float4*)src)[t];
    ushort4 o;
    o.x = f2bf(f.x); o.y = f2bf(f.y); o.z = f2bf(f.z); o.w = f2bf(f.w);
    ((ushort4*)dst)[t] = o;
}

// XCD-pinned CSR fill. Group g = blocks with blockIdx%8==g (one XCD by the
// %8 dispatch heuristic). Each group scans all 2E (edge,direction) entries,
// claiming those whose window ((offs[row])>>shift)&7 == g.
__global__ void fill_csr_kernel(const int* __restrict__ eu, const int* __restrict__ ei,
                                const float* __restrict__ isd,
                                const int* __restrict__ offs,
                                int* __restrict__ cursor, int2* __restrict__ csr,
                                int E, int NU, int shift) {
    int g   = blockIdx.x & 7;
    int gb  = blockIdx.x >> 3;
    int nbg = gridDim.x >> 3;
    int tg  = gb * blockDim.x + threadIdx.x;
    int TG  = nbg * blockDim.x;
    int tot = 2 * E;
    for (int t = tg; t < tot; t += TG) {
        int e = (t < E) ? t : t - E;
        int u = eu[e], v = ei[e];
        int row = (t < E) ? u : NU + v;
        int o = offs[row];
        if (((o >> shift) & 7) != g) continue;      // not my window
        float w = isd[u] * isd[NU + v];
        int src = (t < E) ? v : u;
        csr[atomicAdd(&cursor[row], 1)] = make_int2(src, __float_as_int(w));
    }
}

// l2-normalized weighted sum for one dest row, computed by a 16-lane group.
// Unroll x8: 8 independent feat gathers in flight per group.
__device__ __forceinline__ float4 gather16(const unsigned short* __restrict__ sfeat,
                                           const int2* __restrict__ csr,
                                           int start, int dcount, int l16) {
    float4 acc = make_float4(0.f, 0.f, 0.f, 0.f);
    int j = 0;
    for (; j + 7 < dcount; j += 8) {
        int2 eb[8];
        #pragma unroll
        for (int k = 0; k < 8; ++k) eb[k] = csr[start + j + k];
        ushort4 fb[8];
        #pragma unroll
        for (int k = 0; k < 8; ++k)
            fb[k] = *(const ushort4*)(sfeat + (size_t)eb[k].x * 64 + l16 * 4);
        #pragma unroll
        for (int k = 0; k < 8; ++k) {
            float w = __int_as_float(eb[k].y);
            acc.x = fmaf(w, bf2f(fb[k].x), acc.x);
            acc.y = fmaf(w, bf2f(fb[k].y), acc.y);
            acc.z = fmaf(w, bf2f(fb[k].z), acc.z);
            acc.w = fmaf(w, bf2f(fb[k].w), acc.w);
        }
    }
    for (; j < dcount; ++j) {
        int2 e0 = csr[start + j];
        float w0 = __int_as_float(e0.y);
        ushort4 f0 = *(const ushort4*)(sfeat + (size_t)e0.x * 64 + l16 * 4);
        acc.x = fmaf(w0, bf2f(f0.x), acc.x); acc.y = fmaf(w0, bf2f(f0.y), acc.y);
        acc.z = fmaf(w0, bf2f(f0.z), acc.z); acc.w = fmaf(w0, bf2f(f0.w), acc.w);
    }
    float ss = acc.x * acc.x + acc.y * acc.y + acc.z * acc.z + acc.w * acc.w;
    #pragma unroll
    for (int m = 1; m <= 8; m <<= 1) ss += __shfl_xor(ss, m, 64);  // within 16-lane group
    float scale = 1.f / fmaxf(sqrtf(ss), 1e-12f);
    acc.x *= scale; acc.y *= scale; acc.z *= scale; acc.w *= scale;
    return acc;
}

// 4 rows per wave (one per 16-lane group). Rows [0,NU): users (gather from
// items); [NU,NT): items (gather from users).
__global__ void prop_both_kernel(const unsigned short* __restrict__ uc,
                                 const unsigned short* __restrict__ ic,
                                 unsigned short* __restrict__ ud,
                                 unsigned short* __restrict__ id,
                                 const int* __restrict__ offs, const int* __restrict__ deg,
                                 const int2* __restrict__ csr, int NU, int NT) {
    int t = blockIdx.x * blockDim.x + threadIdx.x;
    int r = t >> 4;                 // global 16-lane group id = row
    if (r >= NT) return;
    int l16 = t & 15;
    const unsigned short* sfeat;
    unsigned short* dst;
    if (r < NU) { sfeat = ic; dst = ud + (size_t)r * 64; }
    else        { sfeat = uc; dst = id + (size_t)(r - NU) * 64; }
    int start  = offs[r];
    int dcount = deg[r];
    float4 a = gather16(sfeat, csr, start, dcount, l16);
    ushort4 o;
    o.x = f2bf(a.x); o.y = f2bf(a.y); o.z = f2bf(a.z); o.w = f2bf(a.w);
    *(ushort4*)(dst + l16 * 4) = o;
}

// Fused epilogue at the 3*B sampled rows:
// out = orig + h1 + 0.5*h2 + (1/3)*l2norm(layer-3 gather).
__global__ void final_kernel(const float* __restrict__ user_feat,
                             const float* __restrict__ item_feat,
                             const unsigned short* __restrict__ uhA,
                             const unsigned short* __restrict__ ihA,
                             const unsigned short* __restrict__ uhB,
                             const unsigned short* __restrict__ ihB,
                             const int* __restrict__ users, const int* __restrict__ pos,
                             const int* __restrict__ neg,
                             const int* __restrict__ offs, const int* __restrict__ deg,
                             const int2* __restrict__ csr, float* __restrict__ out,
                             int NU, int B) {
    int t = blockIdx.x * blockDim.x + threadIdx.x;
    int s = t >> 4;                 // global sample id
    if (s >= 3 * B) return;
    int l16 = t & 15;
    int seg = s / B, b = s - seg * B;
    int r, idx;
    const unsigned short *sfeat, *h1, *h2;
    const float* orig;
    if (seg == 0) {
        idx = users[b]; r = idx;
        sfeat = ihB; orig = user_feat; h1 = uhA; h2 = uhB;
    } else {
        idx = (seg == 1) ? pos[b] : neg[b];
        r = NU + idx;
        sfeat = uhB; orig = item_feat; h1 = ihA; h2 = ihB;
    }
    int start  = offs[r];
    int dcount = deg[r];
    float4 a = gather16(sfeat, csr, start, dcount, l16);
    float4 o = *(const float4*)(orig + (size_t)idx * 64 + l16 * 4);
    ushort4 v1 = *(const ushort4*)(h1 + (size_t)idx * 64 + l16 * 4);
    ushort4 v2 = *(const ushort4*)(h2 + (size_t)idx * 64 + l16 * 4);
    const float c3 = 1.0f / 3.0f;
    o.x += bf2f(v1.x) + 0.5f * bf2f(v2.x) + c3 * a.x;
    o.y += bf2f(v1.y) + 0.5f * bf2f(v2.y) + c3 * a.y;
    o.z += bf2f(v1.z) + 0.5f * bf2f(v2.z) + c3 * a.z;
    o.w += bf2f(v1.w) + 0.5f * bf2f(v2.w) + c3 * a.w;
    *(float4*)(out + (size_t)s * 64 + l16 * 4) = o;
}

extern "C" void kernel_launch(void* const* d_in, const int* in_sizes, int n_in,
                              void* d_out, int out_size, void* d_ws, size_t ws_size,
                              hipStream_t stream) {
    const float* user_feat = (const float*)d_in[0];
    const float* item_feat = (const float*)d_in[1];
    const int* edge_u = (const int*)d_in[2];
    const int* edge_i = (const int*)d_in[3];
    const int* users  = (const int*)d_in[4];
    const int* pos    = (const int*)d_in[5];
    const int* neg    = (const int*)d_in[6];
    float* out = (float*)d_out;

    const int D = 64;
    const int NU = in_sizes[0] / D;
    const int NI = in_sizes[1] / D;
    const int E  = in_sizes[2];
    const int B  = in_sizes[4];
    const int NT = NU + NI;

    char* ws = (char*)d_ws;
    size_t off = 0;
    auto alloc = [&](size_t bytes) -> void* {
        void* p = ws + off;
        off += bytes;
        off = (off + 255) & ~(size_t)255;
        return p;
    };
    // Zero zone: deg (NT) + total (1), contiguous for one memset.
    size_t zbytes = (size_t)(NT + 1) * 4;
    char* zbase = (char*)alloc(zbytes);
    int* deg   = (int*)zbase;
    int* total = deg + NT;
    int*   offs   = (int*)alloc((size_t)NT * 4);
    int*   cursor = (int*)alloc((size_t)NT * 4);
    float* isd    = (float*)alloc((size_t)NT * 4);
    int2*  csr    = (int2*)alloc((size_t)2 * E * 8);
    unsigned short* ufb = (unsigned short*)alloc((size_t)NU * D * 2);
    unsigned short* ifb = (unsigned short*)alloc((size_t)NI * D * 2);
    unsigned short* uhA = (unsigned short*)alloc((size_t)NU * D * 2);
    unsigned short* ihA = (unsigned short*)alloc((size_t)NI * D * 2);
    unsigned short* uhB = (unsigned short*)alloc((size_t)NU * D * 2);
    unsigned short* ihB = (unsigned short*)alloc((size_t)NI * D * 2);

    hipMemsetAsync(zbase, 0, zbytes, stream);

    const int tb = 256;
    count_deg_kernel<<<(E + tb - 1) / tb, tb, 0, stream>>>(edge_u, edge_i, deg, E, NU);
    bump_kernel<<<(NT + tb - 1) / tb, tb, 0, stream>>>(deg, offs, cursor, isd, total, NT);

    int n4u = NU * D / 4, n4i = NI * D / 4;
    conv_bf16_kernel<<<(n4u + tb - 1) / tb, tb, 0, stream>>>(user_feat, ufb, n4u);
    conv_bf16_kernel<<<(n4i + tb - 1) / tb, tb, 0, stream>>>(item_feat, ifb, n4i);

    // Window shift: 8 windows over 2E CSR slots (4MB windows for E=2M).
    int slots = 2 * E;
    int per_win = (slots + 7) / 8;
    int shift = 0;
    while ((1 << shift) < per_win) ++shift;
    fill_csr_kernel<<<2048, tb, 0, stream>>>(edge_u, edge_i, isd, offs,
                                             cursor, csr, E, NU, shift);

    // Layers 1,2 full props (16 threads per row); layer 3 fused into epilogue.
    int pthreads = NT * 16;
    prop_both_kernel<<<(pthreads + tb - 1) / tb, tb, 0, stream>>>(
        ufb, ifb, uhA, ihA, offs, deg, csr, NU, NT);
    prop_both_kernel<<<(pthreads + tb - 1) / tb, tb, 0, stream>>>(
        uhA, ihA, uhB, ihB, offs, deg, csr, NU, NT);
    int fthreads = 3 * B * 16;
    final_kernel<<<(fthreads + tb - 1) / tb, tb, 0, stream>>>(
        user_feat, item_feat, uhA, ihA, uhB, ihB,
        users, pos, neg, offs, deg, csr, out, NU, B);
}